// Round 11
// baseline (2304.904 us; speedup 1.0000x reference)
//
#include <hip/hip_runtime.h>
#include <hip/hip_bf16.h>

// GraphConvLayer: out = relu(A_norm @ (X@W + b))
// Reassociated: Y = A@X (sparse, ~22.5 nnz/row), out = relu(Y@W + rowsum(A)[n]*b[d])
// x: [1024,543,256] f32; W: [256,256] f32; b: [256]; A: [543,543] f32; out: [1024,543,256] f32
//
// R11: bf16-LDS gather. f32 gather moves 13.6GB through the ~64B/cyc/CU TA port
// (354us floor; R8-R10 plateau ~700us). Instead: stage x chunks to LDS as bf16
// (x read once/block, coalesced), gather via ds_read_b64 (6.8GB on the LDS pipe),
// tile CSR entries also in LDS (chain = LDS->LDS). Spill-proof: staging unroll 2,
// y[8]=32 persistent regs, pair-fused gather; audited peak ~110 < 128 cap (512,2).

#define NND    543
#define NROWP  640
#define RPB    64           // rows per block
#define NTILES 9            // tiles per bt
#define CH     64           // x chunk rows
#define NCH    9
#define CAPR   64           // ws CSR slots per row
#define ECAP   36           // LDS-resident entry slots per row (mean 22.5, +2.9 sigma)
#define BTOT   1024
#define GRID   (BTOT*NTILES)   // 9216, %8==0 -> bijective XCD swizzle

typedef __attribute__((ext_vector_type(8))) short short8;
typedef __attribute__((ext_vector_type(4))) float f32x4;

// ---- workspace (bytes) ----
#define WS_ENT 0                          // uint2[640][64] = 327680 {m, f32bits(a)}, zero-padded
#define WS_ST  327680                     // u16[640][12]: [0..9] chunk offsets, [10] cnt, [11] ovf
#define WS_RS  343040                     // f32[640] rowsum
#define WS_W   345600                     // bf16 frags [16][8][64][8] = 131072
#define WS_NEED 476672

// ---- LDS (bytes) ----
#define L_X    0            // x chunk bf16 [64][256] = 32768; Y-swz overlays after gather
#define L_ENT  32768        // uint2[64][36] = 18432; epilogue bounce overlays
#define L_ST   51200        // u16[64][12] = 1536
#define L_RS   52736        // f32[64] = 256
#define L_TOT  52992        // 51.8 KB -> 2 blocks/CU

__device__ __forceinline__ unsigned short f2bf(float f) {   // RNE f32 -> bf16 bits
  unsigned int u = __builtin_bit_cast(unsigned int, f);
  u += 0x7fffu + ((u >> 16) & 1u);
  return (unsigned short)(u >> 16);
}
__device__ __forceinline__ uint2 pack4(const f32x4 v) {
  uint2 u;
  u.x = (unsigned)f2bf(v.x) | ((unsigned)f2bf(v.y) << 16);
  u.y = (unsigned)f2bf(v.z) | ((unsigned)f2bf(v.w) << 16);
  return u;
}
__device__ __forceinline__ float bc(unsigned u) { return __builtin_bit_cast(float, u); }
__device__ __forceinline__ float bflo(unsigned u) { return __builtin_bit_cast(float, u << 16); }
__device__ __forceinline__ float bfhi(unsigned u) { return __builtin_bit_cast(float, u & 0xffff0000u); }
#define FMA4(Y, AV, U) { (Y).x += (AV) * bflo((U).x); (Y).y += (AV) * bfhi((U).x); \
                         (Y).z += (AV) * bflo((U).y); (Y).w += (AV) * bfhi((U).y); }
#define RFL(v) __builtin_amdgcn_readfirstlane(v)

// ---------------- prep: CSR + per-chunk offsets + rowsum (one wave/row) ----------------
__global__ void prep_csr(const float* __restrict__ A, char* __restrict__ ws) {
  const int wid = (blockIdx.x * blockDim.x + threadIdx.x) >> 6;
  const int lane = threadIdx.x & 63;
  if (wid >= NROWP) return;
  uint2* ep = (uint2*)(ws + WS_ENT) + (size_t)wid * CAPR;
  unsigned short* st = (unsigned short*)(ws + WS_ST) + wid * 12;
  float* rs = (float*)(ws + WS_RS);
  if (wid >= NND) {
    for (int k = lane; k < CAPR; k += 64) ep[k] = make_uint2(0u, 0u);
    if (lane < 12) st[lane] = 0;
    if (lane == 0) rs[wid] = 0.f;
    return;
  }
  const float* arow = A + (size_t)wid * NND;
  float s = 0.f; int cnt = 0;
  for (int c = 0; c < NCH; ++c) {
    if (lane == 0) st[c] = (unsigned short)cnt;
    const int m = c * 64 + lane;
    const float a = (m < NND) ? arow[m] : 0.f;
    s += a;
    const unsigned long long mask = __ballot(a != 0.f);
    if (a != 0.f) {
      const int idx = cnt + (int)__popcll(mask & ((1ull << lane) - 1ull));
      if (idx < CAPR) ep[idx] = make_uint2((unsigned)m, __builtin_bit_cast(unsigned, a));
    }
    cnt += (int)__popcll(mask);
  }
  #pragma unroll
  for (int o = 32; o > 0; o >>= 1) s += __shfl_xor(s, o);
  if (cnt <= CAPR) {
    for (int k = cnt + lane; k < CAPR; k += 64) ep[k] = make_uint2(0u, 0u);
  }
  if (lane == 0) {
    st[9] = (unsigned short)cnt;
    st[10] = (unsigned short)cnt;
    st[11] = (cnt > CAPR) ? (unsigned short)1 : (unsigned short)0;
    rs[wid] = s;
  }
}

// ---------------- prep: W -> bf16 MFMA B-fragments [g][ks][lane][8], g = col/16 ----------------
__global__ void prep_w(const float* __restrict__ W, char* __restrict__ ws) {
  const int t = blockIdx.x * 256 + threadIdx.x;
  if (t >= 16 * 8 * 64) return;
  const int lane = t & 63, ks = (t >> 6) & 7, g = t >> 9;
  const int krow = (lane >> 4) * 8, col = g * 16 + (lane & 15);
  unsigned short* dst = (unsigned short*)(ws + WS_W) + (size_t)t * 8;
  #pragma unroll
  for (int e = 0; e < 8; e++) dst[e] = f2bf(W[(ks * 32 + krow + e) * 256 + col]);
}

// ---------------- main ----------------
__global__ __launch_bounds__(512, 2)   // 128 VGPR cap; LDS 51.8KB -> 2 blocks/CU
void gcn_main(const float* __restrict__ x, const float* __restrict__ Wm,
              const float* __restrict__ bias, const float* __restrict__ A,
              float* __restrict__ out, const char* __restrict__ ws, int use_ws)
{
  __shared__ __align__(16) char lds[L_TOT];
  float* rsl = (float*)(lds + L_RS);
  const unsigned short* stl = (const unsigned short*)(lds + L_ST);
  const uint2* entl = (const uint2*)(lds + L_ENT);

  const int tid = threadIdx.x;
  const int w = tid >> 6, lane = tid & 63;
  const int cl = lane & 15, krow = (lane >> 4) * 8;

  // XCD swizzle: the 9 tiles of one bt adjacent -> co-resident on one XCD
  const int p = blockIdx.x;
  const int L = (p & 7) * (GRID / 8) + (p >> 3);
  const int bt = L / NTILES;
  const int tile = L - bt * NTILES;
  const int n0 = tile * RPB;

  const float* xbt = x + (size_t)bt * (NND * 256);
  const uint2* entp = (const uint2*)(ws + WS_ENT);

  // ---- phase 0: tile CSR (st, entries<=36, rowsum) into LDS ----
  if (use_ws) {
    const unsigned* stsrc = (const unsigned*)(ws + WS_ST) + n0 * 6;   // 12 u16 = 6 u32/row
    unsigned* stdst = (unsigned*)(lds + L_ST);
    for (int i = tid; i < RPB * 6; i += 512) stdst[i] = stsrc[i];
    const uint2* esrc = entp + (size_t)n0 * CAPR;
    uint2* edst = (uint2*)(lds + L_ENT);
    for (int i = tid; i < RPB * ECAP; i += 512) {
      const int row = i / ECAP;
      edst[i] = esrc[(size_t)row * CAPR + (i - row * ECAP)];
    }
    if (tid < RPB) rsl[tid] = ((const float*)(ws + WS_RS))[n0 + tid];
  } else {
    unsigned* stdst = (unsigned*)(lds + L_ST);
    for (int i = tid; i < RPB * 6; i += 512) stdst[i] = 0u;
    if (tid < RPB) rsl[tid] = 0.f;
  }

  // ---- gather: Y = A@X; x streamed through LDS as bf16, entries from LDS ----
  f32x4 y[8];
  #pragma unroll
  for (int i = 0; i < 8; i++) y[i] = (f32x4){0.f, 0.f, 0.f, 0.f};
  float racc[8];
  #pragma unroll
  for (int i = 0; i < 8; i++) racc[i] = 0.f;

  for (int c = 0; c < NCH; ++c) {
    const int mbase = c * CH;
    const int rows = min(CH, NND - mbase);
    __syncthreads();                      // prev chunk's reads done (and phase-0 writes visible)
    #pragma unroll 2
    for (int k = 0; k < 8; ++k) {         // stage 64x256 f32 -> bf16, coalesced
      const int slot = tid + (k << 9);
      const int row = slot >> 6, f4 = slot & 63;
      if (row < rows) {
        const float4 v = *(const float4*)(xbt + ((size_t)(mbase + row) << 8) + (f4 << 2));
        f32x4 vv = {v.x, v.y, v.z, v.w};
        *(uint2*)(lds + L_X + (row << 9) + (f4 << 3)) = pack4(vv);
      }
    }
    __syncthreads();

    #pragma unroll
    for (int pr = 0; pr < 4; ++pr) {      // static y[] indices via full unroll
      const int rA = w * 8 + pr * 2, rB = rA + 1;
      if (use_ws) {
        const int cntA = RFL(stl[rA * 12 + 10]), cntB = RFL(stl[rB * 12 + 10]);
        int jA = RFL(stl[rA * 12 + c]);
        const int jA1 = RFL(stl[rA * 12 + c + 1]);
        int jB = RFL(stl[rB * 12 + c]);
        const int jB1 = RFL(stl[rB * 12 + c + 1]);
        if (cntA <= ECAP && cntB <= ECAP) {
          const uint2* eA = entl + rA * ECAP;
          const uint2* eB = entl + rB * ECAP;
          while (jA + 1 < jA1 && jB + 1 < jB1) {
            const uint2 a0 = eA[jA], a1 = eA[jA + 1];
            const uint2 b0 = eB[jB], b1 = eB[jB + 1];
            const uint2 u0 = *(const uint2*)(lds + L_X + (((int)a0.x - mbase) << 9) + (lane << 3));
            const uint2 u1 = *(const uint2*)(lds + L_X + (((int)a1.x - mbase) << 9) + (lane << 3));
            const uint2 u2 = *(const uint2*)(lds + L_X + (((int)b0.x - mbase) << 9) + (lane << 3));
            const uint2 u3 = *(const uint2*)(lds + L_X + (((int)b1.x - mbase) << 9) + (lane << 3));
            FMA4(y[2*pr],   bc(a0.y), u0); FMA4(y[2*pr],   bc(a1.y), u1);
            FMA4(y[2*pr+1], bc(b0.y), u2); FMA4(y[2*pr+1], bc(b1.y), u3);
            jA += 2; jB += 2;
          }
          while (jA + 1 < jA1) {
            const uint2 a0 = eA[jA], a1 = eA[jA + 1];
            const uint2 u0 = *(const uint2*)(lds + L_X + (((int)a0.x - mbase) << 9) + (lane << 3));
            const uint2 u1 = *(const uint2*)(lds + L_X + (((int)a1.x - mbase) << 9) + (lane << 3));
            FMA4(y[2*pr], bc(a0.y), u0); FMA4(y[2*pr], bc(a1.y), u1);
            jA += 2;
          }
          while (jB + 1 < jB1) {
            const uint2 b0 = eB[jB], b1 = eB[jB + 1];
            const uint2 u2 = *(const uint2*)(lds + L_X + (((int)b0.x - mbase) << 9) + (lane << 3));
            const uint2 u3 = *(const uint2*)(lds + L_X + (((int)b1.x - mbase) << 9) + (lane << 3));
            FMA4(y[2*pr+1], bc(b0.y), u2); FMA4(y[2*pr+1], bc(b1.y), u3);
            jB += 2;
          }
          if (jA < jA1) {
            const uint2 a0 = eA[jA];
            const uint2 u0 = *(const uint2*)(lds + L_X + (((int)a0.x - mbase) << 9) + (lane << 3));
            FMA4(y[2*pr], bc(a0.y), u0);
          }
          if (jB < jB1) {
            const uint2 b0 = eB[jB];
            const uint2 u2 = *(const uint2*)(lds + L_X + (((int)b0.x - mbase) << 9) + (lane << 3));
            FMA4(y[2*pr+1], bc(b0.y), u2);
          }
        } else {                          // rare: entries not LDS-resident
          #pragma unroll
          for (int t2 = 0; t2 < 2; ++t2) {
            const int r = rA + t2;
            const int n = n0 + r;
            const int cnt = RFL(stl[r * 12 + 10]);
            if (cnt <= CAPR) {            // sparse from ws (global)
              int j = RFL(stl[r * 12 + c]);
              const int j1 = RFL(stl[r * 12 + c + 1]);
              const uint2* ep = entp + (size_t)n * CAPR;
              for (; j < j1; ++j) {
                const uint2 e = ep[j];
                const uint2 u = *(const uint2*)(lds + L_X + (((int)e.x - mbase) << 9) + (lane << 3));
                FMA4(y[2*pr+t2], bc(e.y), u);
              }
            } else if (n < NND) {         // dense chunk scan
              const float* arow = A + (size_t)n * NND + mbase;
              for (int m = 0; m < rows; ++m) {
                const float a = arow[m];
                if (a != 0.f) {
                  const uint2 u = *(const uint2*)(lds + L_X + (m << 9) + (lane << 3));
                  FMA4(y[2*pr+t2], a, u);
                }
              }
            }
          }
        }
      } else {                            // no-ws fallback: dense + rowsum
        #pragma unroll
        for (int t2 = 0; t2 < 2; ++t2) {
          const int n = n0 + rA + t2;
          if (n < NND) {
            const float* arow = A + (size_t)n * NND + mbase;
            for (int m = 0; m < rows; ++m) {
              const float a = arow[m];
              racc[2*pr+t2] += a;
              if (a != 0.f) {
                const uint2 u = *(const uint2*)(lds + L_X + (m << 9) + (lane << 3));
                FMA4(y[2*pr+t2], a, u);
              }
            }
          }
        }
      }
    }
  }

  if (!use_ws && lane == 0) {
    #pragma unroll
    for (int i = 0; i < 8; i++) rsl[w * 8 + i] = racc[i];
  }

  // ---- Y -> LDS bf16 [64][512B], XOR-swizzled (overlays dead x-chunk buffer) ----
  __syncthreads();
  #pragma unroll
  for (int i = 0; i < 8; ++i) {
    const int r = w * 8 + i;
    *(uint2*)(lds + L_X + r * 512 + ((lane * 8) ^ ((r & 7) << 4))) = pack4(y[i]);
  }
  __syncthreads();

  // ---- MFMA: wave w owns cols [w*32, w*32+32): groups gA=2w, gA+1 ----
  const int gA = 2 * w;
  short8 wfA[8], wfB[8];
  if (use_ws) {
    #pragma unroll
    for (int ks = 0; ks < 8; ++ks) {
      wfA[ks] = *(const short8*)(ws + WS_W + (size_t)(((gA * 8 + ks) * 64 + lane) << 4));
      wfB[ks] = *(const short8*)(ws + WS_W + (size_t)((((gA + 1) * 8 + ks) * 64 + lane) << 4));
    }
  } else {
    #pragma unroll
    for (int ks = 0; ks < 8; ++ks) {
      #pragma unroll
      for (int e = 0; e < 8; ++e) {
        wfA[ks][e] = (short)f2bf(Wm[(ks * 32 + krow + e) * 256 + gA * 16 + cl]);
        wfB[ks][e] = (short)f2bf(Wm[(ks * 32 + krow + e) * 256 + (gA + 1) * 16 + cl]);
      }
    }
  }
  f32x4 accA[4], accB[4];
  #pragma unroll
  for (int mt = 0; mt < 4; ++mt) {
    accA[mt] = (f32x4){0.f, 0.f, 0.f, 0.f};
    accB[mt] = (f32x4){0.f, 0.f, 0.f, 0.f};
  }
  #pragma unroll
  for (int ks = 0; ks < 8; ++ks) {
    #pragma unroll
    for (int mt = 0; mt < 4; ++mt) {
      const int r = mt * 16 + cl;
      const int kb = (ks * 64 + krow * 2) ^ ((r & 7) << 4);
      const short8 af = *(const short8*)(lds + L_X + r * 512 + kb);
      accA[mt] = __builtin_amdgcn_mfma_f32_16x16x32_bf16(af, wfA[ks], accA[mt], 0, 0, 0);
      accB[mt] = __builtin_amdgcn_mfma_f32_16x16x32_bf16(af, wfB[ks], accB[mt], 0, 0, 0);
    }
  }

  // ---- epilogue: bias + relu -> per-wave bounce (overlays entries) -> full-line stores ----
  float* wb = (float*)(lds + L_ENT) + w * (16 * 36);
  const int dA = w * 32 + cl;
  const float bvA = bias[dA], bvB = bias[dA + 16];
  #pragma unroll
  for (int mt = 0; mt < 4; ++mt) {
    #pragma unroll
    for (int q = 0; q < 4; ++q) {
      const int r16 = (lane >> 4) * 4 + q;               // C/D: col=lane&15, row=(lane>>4)*4+q
      const float rsv = rsl[mt * 16 + r16];
      wb[r16 * 36 + cl]      = fmaxf(accA[mt][q] + rsv * bvA, 0.f);
      wb[r16 * 36 + 16 + cl] = fmaxf(accB[mt][q] + rsv * bvB, 0.f);
    }
    asm volatile("s_waitcnt lgkmcnt(0)" ::: "memory");   // wave-lockstep write visibility
    #pragma unroll
    for (int v = 0; v < 2; ++v) {
      const int i = lane * 2 + v;                        // 128 vec4 slots of 16x32 tile
      const int rI = i >> 3, cv = i & 7;
      const int n = n0 + mt * 16 + rI;
      if (n < NND)
        *(f32x4*)(out + ((size_t)bt * NND + n) * 256 + w * 32 + cv * 4) =
            *(const f32x4*)(wb + rI * 36 + cv * 4);
    }
  }
}

extern "C" void kernel_launch(void* const* d_in, const int* in_sizes, int n_in,
                              void* d_out, int out_size, void* d_ws, size_t ws_size,
                              hipStream_t stream) {
  const float* x  = (const float*)d_in[0];
  const float* Wm = (const float*)d_in[1];
  const float* b  = (const float*)d_in[2];
  const float* A  = (const float*)d_in[3];
  float* out = (float*)d_out;
  const int use_ws = (d_ws != nullptr && ws_size >= (size_t)WS_NEED) ? 1 : 0;
  if (use_ws) {
    prep_csr<<<(NROWP * 64 + 255) / 256, 256, 0, stream>>>(A, (char*)d_ws);
    prep_w<<<(16 * 8 * 64 + 255) / 256, 256, 0, stream>>>(Wm, (char*)d_ws);
  }
  gcn_main<<<GRID, 512, 0, stream>>>(x, Wm, b, A, out, (const char*)d_ws, use_ws);
}

// Round 12
// 939.844 us; speedup vs baseline: 2.4524x; 2.4524x over previous
//
#include <hip/hip_runtime.h>
#include <hip/hip_bf16.h>

// GraphConvLayer: out = relu(A_norm @ (X@W + b))
// R12: DENSE two-GEMM MFMA pipeline. The sparse gather (R7-R11) is structurally
// latency/VALU-bound (700-2300us). Dense A@X is only 155 GF on the MFMA pipe.
//   GEMM1: Y[64][256] = A_tile[64][543] @ X_bt[543][256]   (K-chunks of 64)
//   GEMM2: out = relu(Y @ W + rowsum(A)*b)
// A prepacked to MFMA A-fragments (bf16, L2-resident). X chunk staged transposed
// + XOR-swizzled bf16 in LDS. All register arrays statically indexed; ~105 VGPR.

#define NND    543
#define RPB    64           // output rows per block
#define NTILES 9            // tiles per bt (9*64=576 >= 543)
#define NCH    9            // K chunks of 64
#define BTOT   1024
#define GRID   (BTOT*NTILES)   // 9216, %8==0 -> bijective XCD swizzle

typedef __attribute__((ext_vector_type(8))) short short8;
typedef __attribute__((ext_vector_type(4))) float f32x4;

// ---- workspace (bytes) ----
#define WS_A   0                          // bf16 A-frags [tile9][chunk9][f8][lane64][8] = 663552
#define WS_W   663552                     // bf16 W-frags [g16][ks8][lane64][8] = 131072
#define WS_RS  794624                     // f32[576] rowsum (padded)
#define WS_NEED 796928

// ---- LDS (bytes) ----
#define L_XT   0            // Xt bf16 [256 n][128B k-swz] = 32768; Y-swz + bounce overlay later
#define L_A    32768        // A-frag stage [8 frags][64 lanes][16B] = 8192
#define L_RS   40960        // f32[64]
#define L_TOT  41216        // 40.3 KB

__device__ __forceinline__ unsigned short f2bf(float f) {   // RNE f32 -> bf16 bits
  unsigned int u = __builtin_bit_cast(unsigned int, f);
  u += 0x7fffu + ((u >> 16) & 1u);
  return (unsigned short)(u >> 16);
}

// ---------------- prep: A -> bf16 MFMA A-fragments ----------------
// frag f = mt*2+ks; element e: m = tile*64 + mt*16 + (lane&15),
//                              k = chunk*64 + ks*32 + (lane>>4)*8 + e
__global__ void prep_a(const float* __restrict__ A, char* __restrict__ ws) {
  const int t = blockIdx.x * 256 + threadIdx.x;
  if (t >= NTILES * NCH * 8 * 64) return;
  const int lane = t & 63;
  const int f = (t >> 6) & 7;
  const int c = (t >> 9) % NCH;
  const int tile = t / (NCH * 8 * 64);
  const int mt = f >> 1, ks = f & 1;
  const int m = tile * 64 + mt * 16 + (lane & 15);
  const int kb = c * 64 + ks * 32 + (lane >> 4) * 8;
  unsigned short* dst = (unsigned short*)(ws + WS_A) + (size_t)t * 8;
  #pragma unroll
  for (int e = 0; e < 8; ++e) {
    const int k = kb + e;
    dst[e] = (m < NND && k < NND) ? f2bf(A[(size_t)m * NND + k]) : (unsigned short)0;
  }
}

// ---------------- prep: W -> bf16 MFMA B-fragments [g][ks][lane][8], g = col/16 ----------------
__global__ void prep_w(const float* __restrict__ W, char* __restrict__ ws) {
  const int t = blockIdx.x * 256 + threadIdx.x;
  if (t >= 16 * 8 * 64) return;
  const int lane = t & 63, ks = (t >> 6) & 7, g = t >> 9;
  const int krow = (lane >> 4) * 8, col = g * 16 + (lane & 15);
  unsigned short* dst = (unsigned short*)(ws + WS_W) + (size_t)t * 8;
  #pragma unroll
  for (int e = 0; e < 8; e++) dst[e] = f2bf(W[(ks * 32 + krow + e) * 256 + col]);
}

// ---------------- prep: rowsum (one wave per row) ----------------
__global__ void prep_rs(const float* __restrict__ A, char* __restrict__ ws) {
  const int wid = (blockIdx.x * blockDim.x + threadIdx.x) >> 6;
  const int lane = threadIdx.x & 63;
  if (wid >= NTILES * RPB) return;
  float s = 0.f;
  if (wid < NND) {
    const float* arow = A + (size_t)wid * NND;
    for (int m = lane; m < NND; m += 64) s += arow[m];
  }
  #pragma unroll
  for (int o = 32; o > 0; o >>= 1) s += __shfl_xor(s, o);
  if (lane == 0) ((float*)(ws + WS_RS))[wid] = s;
}

// ---------------- main ----------------
__global__ __launch_bounds__(512, 2)   // 128 VGPR cap; LDS 40.3KB
void gcn_main(const float* __restrict__ x, const float* __restrict__ Wm,
              const float* __restrict__ bias, const float* __restrict__ A,
              float* __restrict__ out, const char* __restrict__ ws, int use_ws)
{
  __shared__ __align__(16) char lds[L_TOT];
  float* rsl = (float*)(lds + L_RS);

  const int tid = threadIdx.x;
  const int w = tid >> 6, lane = tid & 63;
  const int cl = lane & 15, krow = (lane >> 4) * 8;

  // XCD swizzle: the 9 tiles of one bt adjacent -> co-resident on one XCD
  const int p = blockIdx.x;
  const int L = (p & 7) * (GRID / 8) + (p >> 3);
  const int bt = L / NTILES;
  const int tile = L - bt * NTILES;
  const int n0 = tile * RPB;

  const float* xbt = x + (size_t)bt * (NND * 256);

  if (use_ws) {
    if (tid < RPB) rsl[tid] = ((const float*)(ws + WS_RS))[n0 + tid];

    // ======== GEMM1: Y = A_tile @ X, K-chunks of 64 ========
    f32x4 acc[8];                         // [mt*2+nt], static indices only
    #pragma unroll
    for (int i = 0; i < 8; ++i) acc[i] = (f32x4){0.f, 0.f, 0.f, 0.f};

    for (int c = 0; c < NCH; ++c) {
      const int kv = min(64, NND - c * 64);        // valid k rows this chunk
      __syncthreads();                             // prev chunk reads done
      // ---- stage Xt[256 n][64 k] bf16, XOR-swizzled; zero k-pad ----
      #pragma unroll 2
      for (int it = 0; it < 8; ++it) {
        const int s = tid + (it << 9);             // 4096 slots: n(256) x kg(16)
        const int n = s & 255, k0 = (s >> 8) * 4;
        float v0 = 0.f, v1 = 0.f, v2 = 0.f, v3 = 0.f;
        if (k0 + 3 < kv) {
          v0 = xbt[(c * 64 + k0 + 0) * 256 + n];
          v1 = xbt[(c * 64 + k0 + 1) * 256 + n];
          v2 = xbt[(c * 64 + k0 + 2) * 256 + n];
          v3 = xbt[(c * 64 + k0 + 3) * 256 + n];
        } else {
          if (k0 + 0 < kv) v0 = xbt[(c * 64 + k0 + 0) * 256 + n];
          if (k0 + 1 < kv) v1 = xbt[(c * 64 + k0 + 1) * 256 + n];
          if (k0 + 2 < kv) v2 = xbt[(c * 64 + k0 + 2) * 256 + n];
          if (k0 + 3 < kv) v3 = xbt[(c * 64 + k0 + 3) * 256 + n];
        }
        uint2 u;
        u.x = (unsigned)f2bf(v0) | ((unsigned)f2bf(v1) << 16);
        u.y = (unsigned)f2bf(v2) | ((unsigned)f2bf(v3) << 16);
        *(uint2*)(lds + L_XT + n * 128 + ((k0 * 2) ^ ((n & 7) << 4))) = u;
      }
      // ---- stage this chunk's 8 A-frags (8KB) ----
      *(uint4*)(lds + L_A + (tid << 4)) =
          *(const uint4*)(ws + WS_A + ((size_t)((tile * NCH + c) * 8 * 64 + tid) << 4));
      __syncthreads();
      // ---- 16 MFMAs ----
      #pragma unroll
      for (int ks = 0; ks < 2; ++ks) {
        short8 af[4], xf[2];
        #pragma unroll
        for (int mt = 0; mt < 4; ++mt)
          af[mt] = *(const short8*)(lds + L_A + (((mt * 2 + ks) * 64 + lane) << 4));
        #pragma unroll
        for (int nt = 0; nt < 2; ++nt) {
          const int n = w * 32 + nt * 16 + cl;
          xf[nt] = *(const short8*)(lds + L_XT + n * 128 +
                                    (((ks * 32 + krow) * 2) ^ ((n & 7) << 4)));
        }
        #pragma unroll
        for (int mt = 0; mt < 4; ++mt)
          #pragma unroll
          for (int nt = 0; nt < 2; ++nt)
            acc[mt * 2 + nt] =
                __builtin_amdgcn_mfma_f32_16x16x32_bf16(af[mt], xf[nt], acc[mt * 2 + nt], 0, 0, 0);
      }
    }

    // ---- Y -> LDS bf16 [64][512B] XOR-swz (overlays dead Xt) ----
    __syncthreads();
    #pragma unroll
    for (int mt = 0; mt < 4; ++mt) {
      #pragma unroll
      for (int nt = 0; nt < 2; ++nt) {
        #pragma unroll
        for (int q = 0; q < 4; ++q) {
          const int row = mt * 16 + (lane >> 4) * 4 + q;   // C/D: col=lane&15, row=(lane>>4)*4+q
          const int col = w * 32 + nt * 16 + cl;
          *(unsigned short*)(lds + L_XT + row * 512 + ((col * 2) ^ ((row & 7) << 4))) =
              f2bf(acc[mt * 2 + nt][q]);
        }
      }
    }
  } else {
    // ---- no-ws fallback: dense per-row f32 gather from global + rowsum ----
    for (int i = 0; i < 8; ++i) {
      const int r = w * 8 + i;
      const int n = n0 + r;
      f32x4 yv = (f32x4){0.f, 0.f, 0.f, 0.f};
      float s = 0.f;
      if (n < NND) {
        const float* arow = A + (size_t)n * NND;
        for (int m = 0; m < NND; ++m) {
          const float a = arow[m];
          s += a;
          if (a != 0.f) yv += a * *(const f32x4*)(xbt + (m << 8) + (lane << 2));
        }
      }
      if (lane == 0) rsl[r] = s;
      uint2 u;
      u.x = (unsigned)f2bf(yv.x) | ((unsigned)f2bf(yv.y) << 16);
      u.y = (unsigned)f2bf(yv.z) | ((unsigned)f2bf(yv.w) << 16);
      *(uint2*)(lds + L_XT + r * 512 + ((lane * 8) ^ ((r & 7) << 4))) = u;
    }
  }
  __syncthreads();

  // ======== GEMM2: out_tile = relu(Y@W + rs*b); wave w owns cols [w*32, w*32+32) ========
  const int gA = 2 * w;
  short8 wfA[8], wfB[8];
  if (use_ws) {
    #pragma unroll
    for (int ks = 0; ks < 8; ++ks) {
      wfA[ks] = *(const short8*)(ws + WS_W + (size_t)(((gA * 8 + ks) * 64 + lane) << 4));
      wfB[ks] = *(const short8*)(ws + WS_W + (size_t)((((gA + 1) * 8 + ks) * 64 + lane) << 4));
    }
  } else {
    #pragma unroll
    for (int ks = 0; ks < 8; ++ks) {
      #pragma unroll
      for (int e = 0; e < 8; ++e) {
        wfA[ks][e] = (short)f2bf(Wm[(ks * 32 + krow + e) * 256 + gA * 16 + cl]);
        wfB[ks][e] = (short)f2bf(Wm[(ks * 32 + krow + e) * 256 + (gA + 1) * 16 + cl]);
      }
    }
  }
  f32x4 accA[4], accB[4];
  #pragma unroll
  for (int mt = 0; mt < 4; ++mt) {
    accA[mt] = (f32x4){0.f, 0.f, 0.f, 0.f};
    accB[mt] = (f32x4){0.f, 0.f, 0.f, 0.f};
  }
  #pragma unroll
  for (int ks = 0; ks < 8; ++ks) {
    #pragma unroll
    for (int mt = 0; mt < 4; ++mt) {
      const int r = mt * 16 + cl;
      const int kb = (ks * 64 + krow * 2) ^ ((r & 7) << 4);
      const short8 af = *(const short8*)(lds + L_XT + r * 512 + kb);
      accA[mt] = __builtin_amdgcn_mfma_f32_16x16x32_bf16(af, wfA[ks], accA[mt], 0, 0, 0);
      accB[mt] = __builtin_amdgcn_mfma_f32_16x16x32_bf16(af, wfB[ks], accB[mt], 0, 0, 0);
    }
  }
  __syncthreads();   // all waves done reading Y before bounce overlays it

  // ---- epilogue: bias + relu -> per-wave bounce -> full 128B-line dwordx4 stores ----
  float* wb = (float*)(lds + L_XT) + w * (16 * 36);
  const int dA = w * 32 + cl;
  const float bvA = bias[dA], bvB = bias[dA + 16];
  #pragma unroll
  for (int mt = 0; mt < 4; ++mt) {
    #pragma unroll
    for (int q = 0; q < 4; ++q) {
      const int r16 = (lane >> 4) * 4 + q;
      const float rsv = rsl[mt * 16 + r16];
      wb[r16 * 36 + cl]      = fmaxf(accA[mt][q] + rsv * bvA, 0.f);
      wb[r16 * 36 + 16 + cl] = fmaxf(accB[mt][q] + rsv * bvB, 0.f);
    }
    asm volatile("s_waitcnt lgkmcnt(0)" ::: "memory");   // per-wave private region
    #pragma unroll
    for (int v = 0; v < 2; ++v) {
      const int i = lane * 2 + v;                        // 128 vec4 slots of 16x32 tile
      const int rI = i >> 3, cv = i & 7;
      const int n = n0 + mt * 16 + rI;
      if (n < NND)
        *(f32x4*)(out + ((size_t)bt * NND + n) * 256 + w * 32 + cv * 4) =
            *(const f32x4*)(wb + rI * 36 + cv * 4);
    }
  }
}

extern "C" void kernel_launch(void* const* d_in, const int* in_sizes, int n_in,
                              void* d_out, int out_size, void* d_ws, size_t ws_size,
                              hipStream_t stream) {
  const float* x  = (const float*)d_in[0];
  const float* Wm = (const float*)d_in[1];
  const float* b  = (const float*)d_in[2];
  const float* A  = (const float*)d_in[3];
  float* out = (float*)d_out;
  const int use_ws = (d_ws != nullptr && ws_size >= (size_t)WS_NEED) ? 1 : 0;
  if (use_ws) {
    prep_a<<<(NTILES * NCH * 8 * 64 + 255) / 256, 256, 0, stream>>>(A, (char*)d_ws);
    prep_w<<<(16 * 8 * 64 + 255) / 256, 256, 0, stream>>>(Wm, (char*)d_ws);
    prep_rs<<<(NTILES * RPB * 64 + 255) / 256, 256, 0, stream>>>(A, (char*)d_ws);
  }
  gcn_main<<<GRID, 512, 0, stream>>>(x, Wm, b, A, out, (const char*)d_ws, use_ws);
}